// Round 10
// baseline (94.618 us; speedup 1.0000x reference)
//
#include <hip/hip_runtime.h>
#include <hip/hip_bf16.h>
#include <math.h>

// Problem constants
#define F_IN  256
#define NOUT  256          // N_HEADS * N_HIDDEN
#define NB    8            // batch
#define NN    1024         // nodes
#define NH    8            // heads
#define ND    32           // hidden per head
#define NROWS (NB * NN)    // 8192
#define LOG2E 1.44269504f

typedef __attribute__((ext_vector_type(8))) short bf16x8;   // 8 bf16 = 4 VGPRs
typedef __attribute__((ext_vector_type(4))) float f32x4;    // MFMA C/D

__device__ inline unsigned pk_bf16(float a, float b) {
    union { __hip_bfloat162 h2; unsigned u; } c;
    c.h2 = __float22bfloat162_rn(make_float2(a, b));
    return c.u;
}
__device__ inline unsigned short bf16u(float a) {
    union { __hip_bfloat16 h; unsigned short u; } c;
    c.h = __float2bfloat16(a);
    return c.u;
}
__device__ inline float bf2f(unsigned short u) {
    union { unsigned u; float f; } c;
    c.u = ((unsigned)u) << 16;
    return c.f;
}
__device__ inline void split8(const float4 va, const float4 vb,
                              bf16x8& hi, bf16x8& lo) {
    float f[8] = {va.x, va.y, va.z, va.w, vb.x, vb.y, vb.z, vb.w};
    union { bf16x8 v; unsigned u[4]; } H, L;
    #pragma unroll
    for (int i = 0; i < 4; ++i) {
        unsigned short h0 = bf16u(f[2 * i]);
        unsigned short h1 = bf16u(f[2 * i + 1]);
        H.u[i] = (unsigned)h0 | ((unsigned)h1 << 16);
        L.u[i] = pk_bf16(f[2 * i] - bf2f(h0), f[2 * i + 1] - bf2f(h1));
    }
    hi = H.v; lo = L.v;
}

// ---------------------------------------------------------------------------
// Kernel 1: g = vertex @ w_vert via split-bf16 MFMA, split-k 2-way.
// R10: each WG processes TWO 64-row blocks sequentially -> grid 512 (halved
// dispatch ramp; w-staging amortized over 2 blocks). LDS = 32 KB staging
// (persistent across halves) + 8 KB combine = 40 KB.
// Grid dim3(NH,64): bid%8 = h -> gT[bh] written XCD-locally for attn.
// Numerics bit-identical to R9.
// ---------------------------------------------------------------------------
__global__ __launch_bounds__(256) void gat_gemm_kernel(
    const float* __restrict__ vertex, const float* __restrict__ w_vert,
    const float* __restrict__ attn_w, unsigned short* __restrict__ gT,
    float* __restrict__ ssT, float* __restrict__ sdT)
{
    // staging: [bk(16 blocks: ktile*2+nt)][lane(64)][8 bf16]; 16 KB each
    __shared__ __align__(16) unsigned short bHi[8192];
    __shared__ __align__(16) unsigned short bLo[8192];
    __shared__ f32x4 comb[2][4][64];     // 8 KB (separate: staging is reused)

    const int t = threadIdx.x, lane = t & 63, wv = t >> 6;
    const int mt = wv & 1, kh = wv >> 1;
    const int il = lane & 15, ql = lane >> 4;
    const int h = blockIdx.x, gr0 = blockIdx.y * 128;
    const int b = gr0 >> 10, bh = b * NH + h;

    // ---- stage w slice once (reused by both halves) ----
    {
        const int n  = t & 31;
        const int kb = t >> 5;               // 0..7
        const int il_s = n & 15, nt_s = n >> 4;
        #pragma unroll
        for (int q = 0; q < 4; ++q) {
            const int k0 = kb * 8 + 64 * q;  // 8-aligned, covers 0..255
            const float* wp = w_vert + (size_t)k0 * NOUT + h * 32 + n;
            float f[8];
            #pragma unroll
            for (int j = 0; j < 8; ++j) f[j] = wp[j * NOUT];
            unsigned hu[4], lu[4];
            #pragma unroll
            for (int j2 = 0; j2 < 4; ++j2) {
                unsigned short h0 = bf16u(f[2 * j2]);
                unsigned short h1 = bf16u(f[2 * j2 + 1]);
                hu[j2] = (unsigned)h0 | ((unsigned)h1 << 16);
                lu[j2] = pk_bf16(f[2 * j2] - bf2f(h0), f[2 * j2 + 1] - bf2f(h1));
            }
            const int ktile = k0 >> 5;           // 0..7
            const int qlb   = (k0 & 31) >> 3;    // 0..3
            const int off   = (ktile * 2 + nt_s) * 512 + (qlb * 16 + il_s) * 8;
            *(uint4*)&bHi[off] = *(const uint4*)hu;
            *(uint4*)&bLo[off] = *(const uint4*)lu;
        }
    }
    __syncthreads();

    for (int half = 0; half < 2; ++half) {
        const int r0 = gr0 + half * 64;
        const float* arow0 = vertex + (size_t)(r0 + mt * 32 + il) * F_IN + kh * 128 + ql * 8;
        const float* arow1 = arow0 + 16 * F_IN;

        f32x4 c00 = {0.f, 0.f, 0.f, 0.f}, c01 = c00, c10 = c00, c11 = c00;

        #pragma unroll
        for (int kk = 0; kk < 4; ++kk) {
            float4 a0a = *(const float4*)(arow0 + kk * 32);
            float4 a0b = *(const float4*)(arow0 + kk * 32 + 4);
            float4 a1a = *(const float4*)(arow1 + kk * 32);
            float4 a1b = *(const float4*)(arow1 + kk * 32 + 4);

            const int bkb = (kh * 4 + kk) * 2;
            bf16x8 bh0 = *(const bf16x8*)&bHi[bkb * 512 + lane * 8];
            bf16x8 bh1 = *(const bf16x8*)&bHi[(bkb + 1) * 512 + lane * 8];
            bf16x8 bl0 = *(const bf16x8*)&bLo[bkb * 512 + lane * 8];
            bf16x8 bl1 = *(const bf16x8*)&bLo[(bkb + 1) * 512 + lane * 8];

            bf16x8 a0hi, a0lo, a1hi, a1lo;
            split8(a0a, a0b, a0hi, a0lo);
            split8(a1a, a1b, a1hi, a1lo);

            c00 = __builtin_amdgcn_mfma_f32_16x16x32_bf16(a0hi, bh0, c00, 0, 0, 0);
            c01 = __builtin_amdgcn_mfma_f32_16x16x32_bf16(a0hi, bh1, c01, 0, 0, 0);
            c10 = __builtin_amdgcn_mfma_f32_16x16x32_bf16(a1hi, bh0, c10, 0, 0, 0);
            c11 = __builtin_amdgcn_mfma_f32_16x16x32_bf16(a1hi, bh1, c11, 0, 0, 0);
            c00 = __builtin_amdgcn_mfma_f32_16x16x32_bf16(a0lo, bh0, c00, 0, 0, 0);
            c01 = __builtin_amdgcn_mfma_f32_16x16x32_bf16(a0lo, bh1, c01, 0, 0, 0);
            c10 = __builtin_amdgcn_mfma_f32_16x16x32_bf16(a1lo, bh0, c10, 0, 0, 0);
            c11 = __builtin_amdgcn_mfma_f32_16x16x32_bf16(a1lo, bh1, c11, 0, 0, 0);
            c00 = __builtin_amdgcn_mfma_f32_16x16x32_bf16(a0hi, bl0, c00, 0, 0, 0);
            c01 = __builtin_amdgcn_mfma_f32_16x16x32_bf16(a0hi, bl1, c01, 0, 0, 0);
            c10 = __builtin_amdgcn_mfma_f32_16x16x32_bf16(a1hi, bl0, c10, 0, 0, 0);
            c11 = __builtin_amdgcn_mfma_f32_16x16x32_bf16(a1hi, bl1, c11, 0, 0, 0);
        }

        // split-k combine (comb reused per half; barrier at top makes it safe)
        __syncthreads();
        if (kh == 1) {
            comb[mt][0][lane] = c00; comb[mt][1][lane] = c01;
            comb[mt][2][lane] = c10; comb[mt][3][lane] = c11;
        }
        __syncthreads();
        if (kh == 0) {
            c00 = c00 + comb[mt][0][lane]; c01 = c01 + comb[mt][1][lane];
            c10 = c10 + comb[mt][2][lane]; c11 = c11 + comb[mt][3][lane];

            const int j0 = (r0 & 1023) + mt * 32;
            const float wsv0 = attn_w[il],      wsv1 = attn_w[16 + il];
            const float wdv0 = attn_w[ND + il], wdv1 = attn_w[ND + 16 + il];

            #pragma unroll
            for (int g = 0; g < 2; ++g) {
                f32x4 cA = g ? c10 : c00;   // d = il
                f32x4 cB = g ? c11 : c01;   // d = 16+il
                const int jr = j0 + g * 16 + ql * 4;

                unsigned g2[2];
                g2[0] = pk_bf16(cA[0], cA[1]); g2[1] = pk_bf16(cA[2], cA[3]);
                *(uint2*)(gT + ((size_t)(bh * ND) + il) * NN + jr) = *(uint2*)g2;
                g2[0] = pk_bf16(cB[0], cB[1]); g2[1] = pk_bf16(cB[2], cB[3]);
                *(uint2*)(gT + ((size_t)(bh * ND) + 16 + il) * NN + jr) = *(uint2*)g2;

                #pragma unroll
                for (int reg = 0; reg < 4; ++reg) {
                    float ps = cA[reg] * wsv0 + cB[reg] * wsv1;
                    float pd = cA[reg] * wdv0 + cB[reg] * wdv1;
                    #pragma unroll
                    for (int off = 1; off < 16; off <<= 1) {
                        ps += __shfl_xor(ps, off);
                        pd += __shfl_xor(pd, off);
                    }
                    if (il == 0) {
                        ssT[bh * NN + jr + reg] = ps;
                        sdT[bh * NN + jr + reg] = pd;
                    }
                }
            }
        }
    }
}

// ---------------------------------------------------------------------------
// Kernel 2 (exp-free MFMA attn):
//   q_ij = max(Ap_i*Bp_j, An_i*Bn_j)  (exact: exp monotone, lrelu=max(x,.2x))
// R10: each WG processes TWO 64-i blocks of one bh sequentially -> grid 512
// (halved dispatch ramp; phase-0 Bp/Bn sweep amortized over 2 blocks).
// 4 waves = j-quarters; 4 m-tiles/wave. bid%8 = h -> XCD-affine with gemm.
// Denominator via ones-B-frag MFMA; quarter-combine LDS tree per half
// (extra barrier before reuse). Numerics bit-identical to R9.
// ---------------------------------------------------------------------------
__global__ __launch_bounds__(256, 4) void gat_attn_kernel(
    const unsigned short* __restrict__ gT, const float* __restrict__ ssT,
    const float* __restrict__ sdT, float* __restrict__ out)
{
    __shared__ __align__(16) float Bp[NN];       // 4 KB
    __shared__ __align__(16) float Bn[NN];       // 4 KB
    __shared__ f32x4 ccomb[2][12][64];           // 24 KB
    __shared__ float red[4];

    const int bid = blockIdx.x;
    const int bh = bid & 63;                 // b*NH + h  (bid%8 = h)
    const int b = bh >> 3, h = bh & 7;
    const int ibase = (bid >> 6) * 128;      // two 64-i blocks
    const int t = threadIdx.x, lane = t & 63, jq = t >> 6;
    const int il = lane & 15, ql = lane >> 4;

    // ---- phase 0 (once): Bp/Bn + global sd max ----
    float sdv[4]; float M = -3.0e38f;
    #pragma unroll
    for (int q = 0; q < 4; ++q) {
        sdv[q] = sdT[bh * NN + t + 256 * q];
        M = fmaxf(M, sdv[q]);
    }
    #pragma unroll
    for (int off = 32; off >= 1; off >>= 1)
        M = fmaxf(M, __shfl_xor(M, off));
    if (lane == 0) red[jq] = M;
    #pragma unroll
    for (int q = 0; q < 4; ++q) {
        Bp[t + 256 * q] = exp2f(sdv[q] * LOG2E);
        Bn[t + 256 * q] = exp2f(0.2f * LOG2E * sdv[q]);
    }
    __syncthreads();
    M = fmaxf(fmaxf(red[0], red[1]), fmaxf(red[2], red[3]));

    const unsigned short* gb0 = gT + ((size_t)(bh * ND) + il) * NN + jq * 256 + ql * 8;
    const unsigned short* gb1 = gb0 + 16 * NN;
    const float* bpq = Bp + jq * 256 + ql * 8;
    const float* bnq = Bn + jq * 256 + ql * 8;

    union { bf16x8 v; unsigned u[4]; } ones;
    ones.u[0] = ones.u[1] = ones.u[2] = ones.u[3] = 0x3F803F80u;

    for (int half = 0; half < 2; ++half) {
        const int i0 = ibase + half * 64;

        float Ap[4], An[4];
        #pragma unroll
        for (int mt = 0; mt < 4; ++mt) {
            const float si = ssT[bh * NN + i0 + mt * 16 + il];
            float x = si + M; x = fmaxf(x, 0.2f * x);
            const float mk = x * LOG2E;
            Ap[mt] = exp2f(fmaf(si, LOG2E, -mk));
            An[mt] = exp2f(fmaf(0.2f * si, LOG2E, -mk));
        }

        f32x4 c0[4], c1[4], cs[4];
        #pragma unroll
        for (int mt = 0; mt < 4; ++mt) {
            c0[mt] = (f32x4){0.f, 0.f, 0.f, 0.f};
            c1[mt] = c0[mt]; cs[mt] = c0[mt];
        }

        // ---- main loop: wave jq handles j in [jq*256, jq*256+256) ----
        #pragma unroll 2
        for (int kk = 0; kk < 256; kk += 32) {
            const float4 p0 = *(const float4*)(bpq + kk);
            const float4 p1 = *(const float4*)(bpq + kk + 4);
            const float4 n0 = *(const float4*)(bnq + kk);
            const float4 n1 = *(const float4*)(bnq + kk + 4);
            const bf16x8 bf0 = *(const bf16x8*)(gb0 + kk);
            const bf16x8 bf1 = *(const bf16x8*)(gb1 + kk);

            float pv[8] = {p0.x, p0.y, p0.z, p0.w, p1.x, p1.y, p1.z, p1.w};
            float nv[8] = {n0.x, n0.y, n0.z, n0.w, n1.x, n1.y, n1.z, n1.w};

            #pragma unroll
            for (int mt = 0; mt < 4; ++mt) {
                float e[8];
                #pragma unroll
                for (int u = 0; u < 8; ++u)
                    e[u] = fmaxf(Ap[mt] * pv[u], An[mt] * nv[u]);
                union { bf16x8 v; unsigned u[4]; } af;
                #pragma unroll
                for (int u = 0; u < 4; ++u)
                    af.u[u] = pk_bf16(e[2 * u], e[2 * u + 1]);
                c0[mt] = __builtin_amdgcn_mfma_f32_16x16x32_bf16(af.v, bf0, c0[mt], 0, 0, 0);
                c1[mt] = __builtin_amdgcn_mfma_f32_16x16x32_bf16(af.v, bf1, c1[mt], 0, 0, 0);
                cs[mt] = __builtin_amdgcn_mfma_f32_16x16x32_bf16(af.v, ones.v, cs[mt], 0, 0, 0);
            }
        }

        // ---- quarter-combine tree (ccomb reused per half -> leading sync) --
        __syncthreads();
        if (jq >= 2) {
            #pragma unroll
            for (int mt = 0; mt < 4; ++mt) {
                ccomb[jq - 2][mt * 3 + 0][lane] = c0[mt];
                ccomb[jq - 2][mt * 3 + 1][lane] = c1[mt];
                ccomb[jq - 2][mt * 3 + 2][lane] = cs[mt];
            }
        }
        __syncthreads();
        if (jq < 2) {
            #pragma unroll
            for (int mt = 0; mt < 4; ++mt) {
                c0[mt] = c0[mt] + ccomb[jq][mt * 3 + 0][lane];
                c1[mt] = c1[mt] + ccomb[jq][mt * 3 + 1][lane];
                cs[mt] = cs[mt] + ccomb[jq][mt * 3 + 2][lane];
            }
        }
        __syncthreads();
        if (jq == 1) {
            #pragma unroll
            for (int mt = 0; mt < 4; ++mt) {
                ccomb[0][mt * 3 + 0][lane] = c0[mt];
                ccomb[0][mt * 3 + 1][lane] = c1[mt];
                ccomb[0][mt * 3 + 2][lane] = cs[mt];
            }
        }
        __syncthreads();
        if (jq == 0) {
            #pragma unroll
            for (int mt = 0; mt < 4; ++mt) {
                c0[mt] = c0[mt] + ccomb[0][mt * 3 + 0][lane];
                c1[mt] = c1[mt] + ccomb[0][mt * 3 + 1][lane];
                cs[mt] = cs[mt] + ccomb[0][mt * 3 + 2][lane];

                // C/D: col=il (d), row=ql*4+reg (i); cs[mt][reg] = S_i
                float* ob = out + (size_t)(b * NN + i0 + mt * 16 + ql * 4) * NOUT + h * ND + il;
                #pragma unroll
                for (int reg = 0; reg < 4; ++reg) {
                    const float r = 1.0f / cs[mt][reg];
                    ob[reg * NOUT]      = c0[mt][reg] * r;
                    ob[reg * NOUT + 16] = c1[mt][reg] * r;
                }
            }
        }
    }
}

// ---------------------------------------------------------------------------
extern "C" void kernel_launch(void* const* d_in, const int* in_sizes, int n_in,
                              void* d_out, int out_size, void* d_ws, size_t ws_size,
                              hipStream_t stream) {
    (void)in_sizes; (void)n_in; (void)out_size; (void)ws_size;
    const float* vertex = (const float*)d_in[0];
    const float* w_vert = (const float*)d_in[1];
    const float* attn_w = (const float*)d_in[2];
    float* out = (float*)d_out;

    char* ws = (char*)d_ws;
    unsigned short* gT = (unsigned short*)ws;                          // 4 MB
    float* ssT = (float*)(ws + ((size_t)NB * NH * ND * NN * 2));
    float* sdT = ssT + (size_t)NB * NH * NN;

    gat_gemm_kernel<<<dim3(NH, 64), 256, 0, stream>>>(vertex, w_vert, attn_w,
                                                      gT, ssT, sdT);
    gat_attn_kernel<<<512, 256, 0, stream>>>(gT, ssT, sdT, out);
}

// Round 11
// 90.314 us; speedup vs baseline: 1.0477x; 1.0477x over previous
//
#include <hip/hip_runtime.h>
#include <hip/hip_bf16.h>
#include <math.h>

// Problem constants
#define F_IN  256
#define NOUT  256          // N_HEADS * N_HIDDEN
#define NB    8            // batch
#define NN    1024         // nodes
#define NH    8            // heads
#define ND    32           // hidden per head
#define NROWS (NB * NN)    // 8192
#define LOG2E 1.44269504f

typedef __attribute__((ext_vector_type(8))) short bf16x8;   // 8 bf16 = 4 VGPRs
typedef __attribute__((ext_vector_type(4))) float f32x4;    // MFMA C/D
typedef __attribute__((ext_vector_type(2))) float f32x2;    // packed fp32

__device__ inline unsigned pk_bf16(float a, float b) {
    union { __hip_bfloat162 h2; unsigned u; } c;
    c.h2 = __float22bfloat162_rn(make_float2(a, b));
    return c.u;
}
__device__ inline unsigned short bf16u(float a) {
    union { __hip_bfloat16 h; unsigned short u; } c;
    c.h = __float2bfloat16(a);
    return c.u;
}
__device__ inline float bf2f(unsigned short u) {
    union { unsigned u; float f; } c;
    c.u = ((unsigned)u) << 16;
    return c.f;
}
__device__ inline void split8(const float4 va, const float4 vb,
                              bf16x8& hi, bf16x8& lo) {
    float f[8] = {va.x, va.y, va.z, va.w, vb.x, vb.y, vb.z, vb.w};
    union { bf16x8 v; unsigned u[4]; } H, L;
    #pragma unroll
    for (int i = 0; i < 4; ++i) {
        unsigned short h0 = bf16u(f[2 * i]);
        unsigned short h1 = bf16u(f[2 * i + 1]);
        H.u[i] = (unsigned)h0 | ((unsigned)h1 << 16);
        L.u[i] = pk_bf16(f[2 * i] - bf2f(h0), f[2 * i + 1] - bf2f(h1));
    }
    hi = H.v; lo = L.v;
}

// ---------------------------------------------------------------------------
// Kernel 1 (exact R9 best config): g = vertex @ w_vert via split-bf16 MFMA,
// split-k 2-way, w-prep folded in (LDS-staged B in MFMA fragment order).
// Grid dim3(NH,128): bid%8 = h -> gT[bh] written XCD-locally for attn.
// ---------------------------------------------------------------------------
__global__ __launch_bounds__(256) void gat_gemm_kernel(
    const float* __restrict__ vertex, const float* __restrict__ w_vert,
    const float* __restrict__ attn_w, unsigned short* __restrict__ gT,
    float* __restrict__ ssT, float* __restrict__ sdT)
{
    // staging: [bk(16 blocks: ktile*2+nt)][lane(64)][8 bf16]; 16 KB each
    __shared__ __align__(16) unsigned short bHi[8192];
    __shared__ __align__(16) unsigned short bLo[8192];
    // combine buffer aliases bHi/bLo after the k-loop (8 KB needed)
    f32x4 (*comb)[4][64] = reinterpret_cast<f32x4(*)[4][64]>(bHi);

    const int t = threadIdx.x, lane = t & 63, wv = t >> 6;
    const int mt = wv & 1, kh = wv >> 1;
    const int il = lane & 15, ql = lane >> 4;
    const int h = blockIdx.x, gr0 = blockIdx.y * 64;
    const int b = gr0 >> 10, bh = b * NH + h;

    // ---- stage w slice: thread t covers n = t&31, k-blocks kb+8q ----
    {
        const int n  = t & 31;
        const int kb = t >> 5;               // 0..7
        const int il_s = n & 15, nt_s = n >> 4;
        #pragma unroll
        for (int q = 0; q < 4; ++q) {
            const int k0 = kb * 8 + 64 * q;  // 8-aligned, covers 0..255
            const float* wp = w_vert + (size_t)k0 * NOUT + h * 32 + n;
            float f[8];
            #pragma unroll
            for (int j = 0; j < 8; ++j) f[j] = wp[j * NOUT];
            unsigned hu[4], lu[4];
            #pragma unroll
            for (int j2 = 0; j2 < 4; ++j2) {
                unsigned short h0 = bf16u(f[2 * j2]);
                unsigned short h1 = bf16u(f[2 * j2 + 1]);
                hu[j2] = (unsigned)h0 | ((unsigned)h1 << 16);
                lu[j2] = pk_bf16(f[2 * j2] - bf2f(h0), f[2 * j2 + 1] - bf2f(h1));
            }
            const int ktile = k0 >> 5;           // 0..7
            const int qlb   = (k0 & 31) >> 3;    // 0..3
            const int off   = (ktile * 2 + nt_s) * 512 + (qlb * 16 + il_s) * 8;
            *(uint4*)&bHi[off] = *(const uint4*)hu;
            *(uint4*)&bLo[off] = *(const uint4*)lu;
        }
    }
    __syncthreads();

    const float* arow0 = vertex + (size_t)(gr0 + mt * 32 + il) * F_IN + kh * 128 + ql * 8;
    const float* arow1 = arow0 + 16 * F_IN;

    f32x4 c00 = {0.f, 0.f, 0.f, 0.f}, c01 = c00, c10 = c00, c11 = c00;

    #pragma unroll
    for (int kk = 0; kk < 4; ++kk) {
        float4 a0a = *(const float4*)(arow0 + kk * 32);
        float4 a0b = *(const float4*)(arow0 + kk * 32 + 4);
        float4 a1a = *(const float4*)(arow1 + kk * 32);
        float4 a1b = *(const float4*)(arow1 + kk * 32 + 4);

        const int bkb = (kh * 4 + kk) * 2;
        bf16x8 bh0 = *(const bf16x8*)&bHi[bkb * 512 + lane * 8];
        bf16x8 bh1 = *(const bf16x8*)&bHi[(bkb + 1) * 512 + lane * 8];
        bf16x8 bl0 = *(const bf16x8*)&bLo[bkb * 512 + lane * 8];
        bf16x8 bl1 = *(const bf16x8*)&bLo[(bkb + 1) * 512 + lane * 8];

        bf16x8 a0hi, a0lo, a1hi, a1lo;
        split8(a0a, a0b, a0hi, a0lo);
        split8(a1a, a1b, a1hi, a1lo);

        c00 = __builtin_amdgcn_mfma_f32_16x16x32_bf16(a0hi, bh0, c00, 0, 0, 0);
        c01 = __builtin_amdgcn_mfma_f32_16x16x32_bf16(a0hi, bh1, c01, 0, 0, 0);
        c10 = __builtin_amdgcn_mfma_f32_16x16x32_bf16(a1hi, bh0, c10, 0, 0, 0);
        c11 = __builtin_amdgcn_mfma_f32_16x16x32_bf16(a1hi, bh1, c11, 0, 0, 0);
        c00 = __builtin_amdgcn_mfma_f32_16x16x32_bf16(a0lo, bh0, c00, 0, 0, 0);
        c01 = __builtin_amdgcn_mfma_f32_16x16x32_bf16(a0lo, bh1, c01, 0, 0, 0);
        c10 = __builtin_amdgcn_mfma_f32_16x16x32_bf16(a1lo, bh0, c10, 0, 0, 0);
        c11 = __builtin_amdgcn_mfma_f32_16x16x32_bf16(a1lo, bh1, c11, 0, 0, 0);
        c00 = __builtin_amdgcn_mfma_f32_16x16x32_bf16(a0hi, bl0, c00, 0, 0, 0);
        c01 = __builtin_amdgcn_mfma_f32_16x16x32_bf16(a0hi, bl1, c01, 0, 0, 0);
        c10 = __builtin_amdgcn_mfma_f32_16x16x32_bf16(a1hi, bl0, c10, 0, 0, 0);
        c11 = __builtin_amdgcn_mfma_f32_16x16x32_bf16(a1hi, bl1, c11, 0, 0, 0);
    }

    // staging LDS is dead from here; alias it as the split-k combine buffer
    __syncthreads();
    if (kh == 1) {
        comb[mt][0][lane] = c00; comb[mt][1][lane] = c01;
        comb[mt][2][lane] = c10; comb[mt][3][lane] = c11;
    }
    __syncthreads();
    if (kh == 0) {
        c00 = c00 + comb[mt][0][lane]; c01 = c01 + comb[mt][1][lane];
        c10 = c10 + comb[mt][2][lane]; c11 = c11 + comb[mt][3][lane];

        const int j0 = (gr0 & 1023) + mt * 32;
        const float wsv0 = attn_w[il],      wsv1 = attn_w[16 + il];
        const float wdv0 = attn_w[ND + il], wdv1 = attn_w[ND + 16 + il];

        #pragma unroll
        for (int g = 0; g < 2; ++g) {
            f32x4 cA = g ? c10 : c00;   // d = il
            f32x4 cB = g ? c11 : c01;   // d = 16+il
            const int jr = j0 + g * 16 + ql * 4;

            unsigned g2[2];
            g2[0] = pk_bf16(cA[0], cA[1]); g2[1] = pk_bf16(cA[2], cA[3]);
            *(uint2*)(gT + ((size_t)(bh * ND) + il) * NN + jr) = *(uint2*)g2;
            g2[0] = pk_bf16(cB[0], cB[1]); g2[1] = pk_bf16(cB[2], cB[3]);
            *(uint2*)(gT + ((size_t)(bh * ND) + 16 + il) * NN + jr) = *(uint2*)g2;

            #pragma unroll
            for (int reg = 0; reg < 4; ++reg) {
                float ps = cA[reg] * wsv0 + cB[reg] * wsv1;
                float pd = cA[reg] * wdv0 + cB[reg] * wdv1;
                #pragma unroll
                for (int off = 1; off < 16; off <<= 1) {
                    ps += __shfl_xor(ps, off);
                    pd += __shfl_xor(pd, off);
                }
                if (il == 0) {
                    ssT[bh * NN + jr + reg] = ps;
                    sdT[bh * NN + jr + reg] = pd;
                }
            }
        }
    }
}

// ---------------------------------------------------------------------------
// Kernel 2 (exp-free MFMA attn, R7/R9 best config + PACKED-FP32 q-gen):
//   q_ij = max(Ap_i*Bp_j, An_i*Bn_j)  (exact: exp monotone, lrelu=max(x,.2x))
// Hot-loop q-gen now operates on float2 vectors so the backend can emit
// v_pk_mul_f32 / v_pk_max_f32: 28 -> 16 VALU inst per m-tile per iteration
// (IEEE-identical results, same order). Everything else identical to R9.
// WG = 64 i-rows; 4 waves = j-quarters; 4 m-tiles/wave; grid 1024 (bid%8=h
// -> XCD-affine with gemm). Denominator via ones-B-frag MFMA.
// ---------------------------------------------------------------------------
__global__ __launch_bounds__(256, 4) void gat_attn_kernel(
    const unsigned short* __restrict__ gT, const float* __restrict__ ssT,
    const float* __restrict__ sdT, float* __restrict__ out)
{
    __shared__ __align__(16) float Bp[NN];       // 4 KB
    __shared__ __align__(16) float Bn[NN];       // 4 KB
    __shared__ f32x4 ccomb[2][12][64];           // 24 KB
    __shared__ float red[4];

    const int bid = blockIdx.x;
    const int bh = bid & 63;                 // b*NH + h  (bid%8 = h)
    const int b = bh >> 3, h = bh & 7;
    const int i0 = (bid >> 6) * 64;
    const int t = threadIdx.x, lane = t & 63, jq = t >> 6;
    const int il = lane & 15, ql = lane >> 4;

    // ---- phase 0: Bp/Bn + global sd max + per-lane i-constants ----
    float sdv[4]; float M = -3.0e38f;
    #pragma unroll
    for (int q = 0; q < 4; ++q) {
        sdv[q] = sdT[bh * NN + t + 256 * q];
        M = fmaxf(M, sdv[q]);
    }
    #pragma unroll
    for (int off = 32; off >= 1; off >>= 1)
        M = fmaxf(M, __shfl_xor(M, off));
    if (lane == 0) red[jq] = M;
    #pragma unroll
    for (int q = 0; q < 4; ++q) {
        Bp[t + 256 * q] = exp2f(sdv[q] * LOG2E);
        Bn[t + 256 * q] = exp2f(0.2f * LOG2E * sdv[q]);
    }
    __syncthreads();
    M = fmaxf(fmaxf(red[0], red[1]), fmaxf(red[2], red[3]));

    f32x2 Ap2[4], An2[4];
    #pragma unroll
    for (int mt = 0; mt < 4; ++mt) {
        const float si = ssT[bh * NN + i0 + mt * 16 + il];
        float x = si + M; x = fmaxf(x, 0.2f * x);
        const float mk = x * LOG2E;
        const float ap = exp2f(fmaf(si, LOG2E, -mk));
        const float an = exp2f(fmaf(0.2f * si, LOG2E, -mk));
        Ap2[mt] = (f32x2){ap, ap};
        An2[mt] = (f32x2){an, an};
    }

    const unsigned short* gb0 = gT + ((size_t)(bh * ND) + il) * NN + jq * 256 + ql * 8;
    const unsigned short* gb1 = gb0 + 16 * NN;
    const float* bpq = Bp + jq * 256 + ql * 8;
    const float* bnq = Bn + jq * 256 + ql * 8;

    union { bf16x8 v; unsigned u[4]; } ones;
    ones.u[0] = ones.u[1] = ones.u[2] = ones.u[3] = 0x3F803F80u;

    f32x4 c0[4], c1[4], cs[4];
    #pragma unroll
    for (int mt = 0; mt < 4; ++mt) {
        c0[mt] = (f32x4){0.f, 0.f, 0.f, 0.f};
        c1[mt] = c0[mt]; cs[mt] = c0[mt];
    }

    // ---- main loop: wave jq handles j in [jq*256, jq*256+256) ----
    #pragma unroll 2
    for (int kk = 0; kk < 256; kk += 32) {
        f32x2 pv2[4], nv2[4];
        #pragma unroll
        for (int u = 0; u < 4; ++u) {
            pv2[u] = *(const f32x2*)(bpq + kk + 2 * u);
            nv2[u] = *(const f32x2*)(bnq + kk + 2 * u);
        }
        const bf16x8 bf0 = *(const bf16x8*)(gb0 + kk);
        const bf16x8 bf1 = *(const bf16x8*)(gb1 + kk);

        #pragma unroll
        for (int mt = 0; mt < 4; ++mt) {
            union { bf16x8 v; unsigned u[4]; } af;
            #pragma unroll
            for (int u = 0; u < 4; ++u) {
                // packed: v_pk_mul_f32 x2 + v_pk_max_f32 + v_cvt_pk_bf16
                f32x2 e2 = __builtin_elementwise_max(Ap2[mt] * pv2[u],
                                                     An2[mt] * nv2[u]);
                af.u[u] = pk_bf16(e2.x, e2.y);
            }
            c0[mt] = __builtin_amdgcn_mfma_f32_16x16x32_bf16(af.v, bf0, c0[mt], 0, 0, 0);
            c1[mt] = __builtin_amdgcn_mfma_f32_16x16x32_bf16(af.v, bf1, c1[mt], 0, 0, 0);
            cs[mt] = __builtin_amdgcn_mfma_f32_16x16x32_bf16(af.v, ones.v, cs[mt], 0, 0, 0);
        }
    }

    // ---- quarter-combine tree: 2,3 -> 0,1; then 1 -> 0 ----
    if (jq >= 2) {
        #pragma unroll
        for (int mt = 0; mt < 4; ++mt) {
            ccomb[jq - 2][mt * 3 + 0][lane] = c0[mt];
            ccomb[jq - 2][mt * 3 + 1][lane] = c1[mt];
            ccomb[jq - 2][mt * 3 + 2][lane] = cs[mt];
        }
    }
    __syncthreads();
    if (jq < 2) {
        #pragma unroll
        for (int mt = 0; mt < 4; ++mt) {
            c0[mt] = c0[mt] + ccomb[jq][mt * 3 + 0][lane];
            c1[mt] = c1[mt] + ccomb[jq][mt * 3 + 1][lane];
            cs[mt] = cs[mt] + ccomb[jq][mt * 3 + 2][lane];
        }
    }
    __syncthreads();
    if (jq == 1) {
        #pragma unroll
        for (int mt = 0; mt < 4; ++mt) {
            ccomb[0][mt * 3 + 0][lane] = c0[mt];
            ccomb[0][mt * 3 + 1][lane] = c1[mt];
            ccomb[0][mt * 3 + 2][lane] = cs[mt];
        }
    }
    __syncthreads();
    if (jq == 0) {
        #pragma unroll
        for (int mt = 0; mt < 4; ++mt) {
            c0[mt] = c0[mt] + ccomb[0][mt * 3 + 0][lane];
            c1[mt] = c1[mt] + ccomb[0][mt * 3 + 1][lane];
            cs[mt] = cs[mt] + ccomb[0][mt * 3 + 2][lane];

            // C/D: col=il (d), row=ql*4+reg (i); cs[mt][reg] = S_i
            float* ob = out + (size_t)(b * NN + i0 + mt * 16 + ql * 4) * NOUT + h * ND + il;
            #pragma unroll
            for (int reg = 0; reg < 4; ++reg) {
                const float r = 1.0f / cs[mt][reg];
                ob[reg * NOUT]      = c0[mt][reg] * r;
                ob[reg * NOUT + 16] = c1[mt][reg] * r;
            }
        }
    }
}

// ---------------------------------------------------------------------------
extern "C" void kernel_launch(void* const* d_in, const int* in_sizes, int n_in,
                              void* d_out, int out_size, void* d_ws, size_t ws_size,
                              hipStream_t stream) {
    (void)in_sizes; (void)n_in; (void)out_size; (void)ws_size;
    const float* vertex = (const float*)d_in[0];
    const float* w_vert = (const float*)d_in[1];
    const float* attn_w = (const float*)d_in[2];
    float* out = (float*)d_out;

    char* ws = (char*)d_ws;
    unsigned short* gT = (unsigned short*)ws;                          // 4 MB
    float* ssT = (float*)(ws + ((size_t)NB * NH * ND * NN * 2));
    float* sdT = ssT + (size_t)NB * NH * NN;

    gat_gemm_kernel<<<dim3(NH, 128), 256, 0, stream>>>(vertex, w_vert, attn_w,
                                                       gT, ssT, sdT);
    gat_attn_kernel<<<1024, 256, 0, stream>>>(gT, ssT, sdT, out);
}

// Round 12
// 89.602 us; speedup vs baseline: 1.0560x; 1.0079x over previous
//
#include <hip/hip_runtime.h>
#include <hip/hip_bf16.h>
#include <math.h>

// Problem constants
#define F_IN  256
#define NOUT  256          // N_HEADS * N_HIDDEN
#define NB    8            // batch
#define NN    1024         // nodes
#define NH    8            // heads
#define ND    32           // hidden per head
#define NROWS (NB * NN)    // 8192
#define LOG2E 1.44269504f

typedef __attribute__((ext_vector_type(8))) short bf16x8;   // 8 bf16 = 4 VGPRs
typedef __attribute__((ext_vector_type(4))) float f32x4;    // MFMA C/D
typedef __attribute__((ext_vector_type(2))) float f32x2;    // packed fp32

__device__ inline unsigned pk_bf16(float a, float b) {
    union { __hip_bfloat162 h2; unsigned u; } c;
    c.h2 = __float22bfloat162_rn(make_float2(a, b));
    return c.u;
}
__device__ inline unsigned short bf16u(float a) {
    union { __hip_bfloat16 h; unsigned short u; } c;
    c.h = __float2bfloat16(a);
    return c.u;
}
__device__ inline float bf2f(unsigned short u) {
    union { unsigned u; float f; } c;
    c.u = ((unsigned)u) << 16;
    return c.f;
}
__device__ inline void split8(const float4 va, const float4 vb,
                              bf16x8& hi, bf16x8& lo) {
    float f[8] = {va.x, va.y, va.z, va.w, vb.x, vb.y, vb.z, vb.w};
    union { bf16x8 v; unsigned u[4]; } H, L;
    #pragma unroll
    for (int i = 0; i < 4; ++i) {
        unsigned short h0 = bf16u(f[2 * i]);
        unsigned short h1 = bf16u(f[2 * i + 1]);
        H.u[i] = (unsigned)h0 | ((unsigned)h1 << 16);
        L.u[i] = pk_bf16(f[2 * i] - bf2f(h0), f[2 * i + 1] - bf2f(h1));
    }
    hi = H.v; lo = L.v;
}

// ---------------------------------------------------------------------------
// Kernel 1: g = vertex @ w_vert via split-bf16 MFMA, split-k 2-way, w-prep
// folded in (LDS-staged B in MFMA fragment order). R12: gT stores now go
// through a padded LDS transpose (32x72 ushort, aliased into dead staging
// LDS) so global writes are contiguous 16 B/lane (128-B segments) instead of
// 8 B at 2 KB stride (64 sub-line transactions/instr, ~8x amplification).
// Grid dim3(NH,128): bid%8 = h -> gT[bh] written XCD-locally for attn.
// ---------------------------------------------------------------------------
__global__ __launch_bounds__(256) void gat_gemm_kernel(
    const float* __restrict__ vertex, const float* __restrict__ w_vert,
    const float* __restrict__ attn_w, unsigned short* __restrict__ gT,
    float* __restrict__ ssT, float* __restrict__ sdT)
{
    // staging: [bk(16 blocks: ktile*2+nt)][lane(64)][8 bf16]; 16 KB each
    __shared__ __align__(16) unsigned short bHi[8192];
    __shared__ __align__(16) unsigned short bLo[8192];
    // after the k-loop the staging LDS is dead:
    //   comb  aliases bHi (8 KB needed)
    //   trans aliases bLo (32 x 72 ushort = 4.5 KB, row stride 144 B = 9x16)
    f32x4 (*comb)[4][64] = reinterpret_cast<f32x4(*)[4][64]>(bHi);
    unsigned short (*trans)[72] = reinterpret_cast<unsigned short(*)[72]>(bLo);

    const int t = threadIdx.x, lane = t & 63, wv = t >> 6;
    const int mt = wv & 1, kh = wv >> 1;
    const int il = lane & 15, ql = lane >> 4;
    const int h = blockIdx.x, gr0 = blockIdx.y * 64;
    const int b = gr0 >> 10, bh = b * NH + h;

    // ---- stage w slice: thread t covers n = t&31, k-blocks kb+8q ----
    {
        const int n  = t & 31;
        const int kb = t >> 5;               // 0..7
        const int il_s = n & 15, nt_s = n >> 4;
        #pragma unroll
        for (int q = 0; q < 4; ++q) {
            const int k0 = kb * 8 + 64 * q;  // 8-aligned, covers 0..255
            const float* wp = w_vert + (size_t)k0 * NOUT + h * 32 + n;
            float f[8];
            #pragma unroll
            for (int j = 0; j < 8; ++j) f[j] = wp[j * NOUT];
            unsigned hu[4], lu[4];
            #pragma unroll
            for (int j2 = 0; j2 < 4; ++j2) {
                unsigned short h0 = bf16u(f[2 * j2]);
                unsigned short h1 = bf16u(f[2 * j2 + 1]);
                hu[j2] = (unsigned)h0 | ((unsigned)h1 << 16);
                lu[j2] = pk_bf16(f[2 * j2] - bf2f(h0), f[2 * j2 + 1] - bf2f(h1));
            }
            const int ktile = k0 >> 5;           // 0..7
            const int qlb   = (k0 & 31) >> 3;    // 0..3
            const int off   = (ktile * 2 + nt_s) * 512 + (qlb * 16 + il_s) * 8;
            *(uint4*)&bHi[off] = *(const uint4*)hu;
            *(uint4*)&bLo[off] = *(const uint4*)lu;
        }
    }
    __syncthreads();

    const float* arow0 = vertex + (size_t)(gr0 + mt * 32 + il) * F_IN + kh * 128 + ql * 8;
    const float* arow1 = arow0 + 16 * F_IN;

    f32x4 c00 = {0.f, 0.f, 0.f, 0.f}, c01 = c00, c10 = c00, c11 = c00;

    #pragma unroll
    for (int kk = 0; kk < 4; ++kk) {
        float4 a0a = *(const float4*)(arow0 + kk * 32);
        float4 a0b = *(const float4*)(arow0 + kk * 32 + 4);
        float4 a1a = *(const float4*)(arow1 + kk * 32);
        float4 a1b = *(const float4*)(arow1 + kk * 32 + 4);

        const int bkb = (kh * 4 + kk) * 2;
        bf16x8 bh0 = *(const bf16x8*)&bHi[bkb * 512 + lane * 8];
        bf16x8 bh1 = *(const bf16x8*)&bHi[(bkb + 1) * 512 + lane * 8];
        bf16x8 bl0 = *(const bf16x8*)&bLo[bkb * 512 + lane * 8];
        bf16x8 bl1 = *(const bf16x8*)&bLo[(bkb + 1) * 512 + lane * 8];

        bf16x8 a0hi, a0lo, a1hi, a1lo;
        split8(a0a, a0b, a0hi, a0lo);
        split8(a1a, a1b, a1hi, a1lo);

        c00 = __builtin_amdgcn_mfma_f32_16x16x32_bf16(a0hi, bh0, c00, 0, 0, 0);
        c01 = __builtin_amdgcn_mfma_f32_16x16x32_bf16(a0hi, bh1, c01, 0, 0, 0);
        c10 = __builtin_amdgcn_mfma_f32_16x16x32_bf16(a1hi, bh0, c10, 0, 0, 0);
        c11 = __builtin_amdgcn_mfma_f32_16x16x32_bf16(a1hi, bh1, c11, 0, 0, 0);
        c00 = __builtin_amdgcn_mfma_f32_16x16x32_bf16(a0lo, bh0, c00, 0, 0, 0);
        c01 = __builtin_amdgcn_mfma_f32_16x16x32_bf16(a0lo, bh1, c01, 0, 0, 0);
        c10 = __builtin_amdgcn_mfma_f32_16x16x32_bf16(a1lo, bh0, c10, 0, 0, 0);
        c11 = __builtin_amdgcn_mfma_f32_16x16x32_bf16(a1lo, bh1, c11, 0, 0, 0);
        c00 = __builtin_amdgcn_mfma_f32_16x16x32_bf16(a0hi, bl0, c00, 0, 0, 0);
        c01 = __builtin_amdgcn_mfma_f32_16x16x32_bf16(a0hi, bl1, c01, 0, 0, 0);
        c10 = __builtin_amdgcn_mfma_f32_16x16x32_bf16(a1hi, bl0, c10, 0, 0, 0);
        c11 = __builtin_amdgcn_mfma_f32_16x16x32_bf16(a1hi, bl1, c11, 0, 0, 0);
    }

    // staging LDS dead from here; alias as combine + transpose buffers
    __syncthreads();
    if (kh == 1) {
        comb[mt][0][lane] = c00; comb[mt][1][lane] = c01;
        comb[mt][2][lane] = c10; comb[mt][3][lane] = c11;
    }
    __syncthreads();
    if (kh == 0) {
        c00 = c00 + comb[mt][0][lane]; c01 = c01 + comb[mt][1][lane];
        c10 = c10 + comb[mt][2][lane]; c11 = c11 + comb[mt][3][lane];

        const float wsv0 = attn_w[il],      wsv1 = attn_w[16 + il];
        const float wdv0 = attn_w[ND + il], wdv1 = attn_w[ND + 16 + il];
        const int j0 = (gr0 & 1023) + mt * 32;

        #pragma unroll
        for (int g = 0; g < 2; ++g) {
            f32x4 cA = g ? c10 : c00;   // d = il
            f32x4 cB = g ? c11 : c01;   // d = 16+il
            const int jl = mt * 32 + g * 16 + ql * 4;   // local j in [0,64)

            // transpose into padded LDS (same bf16 rounding as before)
            *(unsigned*)&trans[il][jl]          = pk_bf16(cA[0], cA[1]);
            *(unsigned*)&trans[il][jl + 2]      = pk_bf16(cA[2], cA[3]);
            *(unsigned*)&trans[16 + il][jl]     = pk_bf16(cB[0], cB[1]);
            *(unsigned*)&trans[16 + il][jl + 2] = pk_bf16(cB[2], cB[3]);

            const int jr = j0 + g * 16 + ql * 4;
            #pragma unroll
            for (int reg = 0; reg < 4; ++reg) {
                float ps = cA[reg] * wsv0 + cB[reg] * wsv1;
                float pd = cA[reg] * wdv0 + cB[reg] * wdv1;
                #pragma unroll
                for (int off = 1; off < 16; off <<= 1) {
                    ps += __shfl_xor(ps, off);
                    pd += __shfl_xor(pd, off);
                }
                if (il == 0) {
                    ssT[bh * NN + jr + reg] = ps;
                    sdT[bh * NN + jr + reg] = pd;
                }
            }
        }
    }
    __syncthreads();

    // coalesced gT store: thread t -> d = t>>3, 8 consecutive j (16 B)
    {
        const int d  = t >> 3;
        const int jo = (t & 7) * 8;
        uint4 v = *(const uint4*)&trans[d][jo];
        *(uint4*)(gT + ((size_t)(bh * ND) + d) * NN + (gr0 & 1023) + jo) = v;
    }
}

// ---------------------------------------------------------------------------
// Kernel 2 (exp-free MFMA attn, best config, packed-fp32 q-gen):
//   q_ij = max(Ap_i*Bp_j, An_i*Bn_j)  (exact: exp monotone, lrelu=max(x,.2x))
// WG = 64 i-rows; 4 waves = j-quarters; 4 m-tiles/wave; grid 1024 (bid%8=h
// -> XCD-affine with gemm). Denominator via ones-B-frag MFMA; barrier-free
// main loop; quarter-combine LDS tree.
// ---------------------------------------------------------------------------
__global__ __launch_bounds__(256, 4) void gat_attn_kernel(
    const unsigned short* __restrict__ gT, const float* __restrict__ ssT,
    const float* __restrict__ sdT, float* __restrict__ out)
{
    __shared__ __align__(16) float Bp[NN];       // 4 KB
    __shared__ __align__(16) float Bn[NN];       // 4 KB
    __shared__ f32x4 ccomb[2][12][64];           // 24 KB
    __shared__ float red[4];

    const int bid = blockIdx.x;
    const int bh = bid & 63;                 // b*NH + h  (bid%8 = h)
    const int b = bh >> 3, h = bh & 7;
    const int i0 = (bid >> 6) * 64;
    const int t = threadIdx.x, lane = t & 63, jq = t >> 6;
    const int il = lane & 15, ql = lane >> 4;

    // ---- phase 0: Bp/Bn + global sd max + per-lane i-constants ----
    float sdv[4]; float M = -3.0e38f;
    #pragma unroll
    for (int q = 0; q < 4; ++q) {
        sdv[q] = sdT[bh * NN + t + 256 * q];
        M = fmaxf(M, sdv[q]);
    }
    #pragma unroll
    for (int off = 32; off >= 1; off >>= 1)
        M = fmaxf(M, __shfl_xor(M, off));
    if (lane == 0) red[jq] = M;
    #pragma unroll
    for (int q = 0; q < 4; ++q) {
        Bp[t + 256 * q] = exp2f(sdv[q] * LOG2E);
        Bn[t + 256 * q] = exp2f(0.2f * LOG2E * sdv[q]);
    }
    __syncthreads();
    M = fmaxf(fmaxf(red[0], red[1]), fmaxf(red[2], red[3]));

    f32x2 Ap2[4], An2[4];
    #pragma unroll
    for (int mt = 0; mt < 4; ++mt) {
        const float si = ssT[bh * NN + i0 + mt * 16 + il];
        float x = si + M; x = fmaxf(x, 0.2f * x);
        const float mk = x * LOG2E;
        const float ap = exp2f(fmaf(si, LOG2E, -mk));
        const float an = exp2f(fmaf(0.2f * si, LOG2E, -mk));
        Ap2[mt] = (f32x2){ap, ap};
        An2[mt] = (f32x2){an, an};
    }

    const unsigned short* gb0 = gT + ((size_t)(bh * ND) + il) * NN + jq * 256 + ql * 8;
    const unsigned short* gb1 = gb0 + 16 * NN;
    const float* bpq = Bp + jq * 256 + ql * 8;
    const float* bnq = Bn + jq * 256 + ql * 8;

    union { bf16x8 v; unsigned u[4]; } ones;
    ones.u[0] = ones.u[1] = ones.u[2] = ones.u[3] = 0x3F803F80u;

    f32x4 c0[4], c1[4], cs[4];
    #pragma unroll
    for (int mt = 0; mt < 4; ++mt) {
        c0[mt] = (f32x4){0.f, 0.f, 0.f, 0.f};
        c1[mt] = c0[mt]; cs[mt] = c0[mt];
    }

    // ---- main loop: wave jq handles j in [jq*256, jq*256+256) ----
    #pragma unroll 2
    for (int kk = 0; kk < 256; kk += 32) {
        f32x2 pv2[4], nv2[4];
        #pragma unroll
        for (int u = 0; u < 4; ++u) {
            pv2[u] = *(const f32x2*)(bpq + kk + 2 * u);
            nv2[u] = *(const f32x2*)(bnq + kk + 2 * u);
        }
        const bf16x8 bf0 = *(const bf16x8*)(gb0 + kk);
        const bf16x8 bf1 = *(const bf16x8*)(gb1 + kk);

        #pragma unroll
        for (int mt = 0; mt < 4; ++mt) {
            union { bf16x8 v; unsigned u[4]; } af;
            #pragma unroll
            for (int u = 0; u < 4; ++u) {
                f32x2 e2 = __builtin_elementwise_max(Ap2[mt] * pv2[u],
                                                     An2[mt] * nv2[u]);
                af.u[u] = pk_bf16(e2.x, e2.y);
            }
            c0[mt] = __builtin_amdgcn_mfma_f32_16x16x32_bf16(af.v, bf0, c0[mt], 0, 0, 0);
            c1[mt] = __builtin_amdgcn_mfma_f32_16x16x32_bf16(af.v, bf1, c1[mt], 0, 0, 0);
            cs[mt] = __builtin_amdgcn_mfma_f32_16x16x32_bf16(af.v, ones.v, cs[mt], 0, 0, 0);
        }
    }

    // ---- quarter-combine tree: 2,3 -> 0,1; then 1 -> 0 ----
    if (jq >= 2) {
        #pragma unroll
        for (int mt = 0; mt < 4; ++mt) {
            ccomb[jq - 2][mt * 3 + 0][lane] = c0[mt];
            ccomb[jq - 2][mt * 3 + 1][lane] = c1[mt];
            ccomb[jq - 2][mt * 3 + 2][lane] = cs[mt];
        }
    }
    __syncthreads();
    if (jq < 2) {
        #pragma unroll
        for (int mt = 0; mt < 4; ++mt) {
            c0[mt] = c0[mt] + ccomb[jq][mt * 3 + 0][lane];
            c1[mt] = c1[mt] + ccomb[jq][mt * 3 + 1][lane];
            cs[mt] = cs[mt] + ccomb[jq][mt * 3 + 2][lane];
        }
    }
    __syncthreads();
    if (jq == 1) {
        #pragma unroll
        for (int mt = 0; mt < 4; ++mt) {
            ccomb[0][mt * 3 + 0][lane] = c0[mt];
            ccomb[0][mt * 3 + 1][lane] = c1[mt];
            ccomb[0][mt * 3 + 2][lane] = cs[mt];
        }
    }
    __syncthreads();
    if (jq == 0) {
        #pragma unroll
        for (int mt = 0; mt < 4; ++mt) {
            c0[mt] = c0[mt] + ccomb[0][mt * 3 + 0][lane];
            c1[mt] = c1[mt] + ccomb[0][mt * 3 + 1][lane];
            cs[mt] = cs[mt] + ccomb[0][mt * 3 + 2][lane];

            // C/D: col=il (d), row=ql*4+reg (i); cs[mt][reg] = S_i
            float* ob = out + (size_t)(b * NN + i0 + mt * 16 + ql * 4) * NOUT + h * ND + il;
            #pragma unroll
            for (int reg = 0; reg < 4; ++reg) {
                const float r = 1.0f / cs[mt][reg];
                ob[reg * NOUT]      = c0[mt][reg] * r;
                ob[reg * NOUT + 16] = c1[mt][reg] * r;
            }
        }
    }
}

// ---------------------------------------------------------------------------
extern "C" void kernel_launch(void* const* d_in, const int* in_sizes, int n_in,
                              void* d_out, int out_size, void* d_ws, size_t ws_size,
                              hipStream_t stream) {
    (void)in_sizes; (void)n_in; (void)out_size; (void)ws_size;
    const float* vertex = (const float*)d_in[0];
    const float* w_vert = (const float*)d_in[1];
    const float* attn_w = (const float*)d_in[2];
    float* out = (float*)d_out;

    char* ws = (char*)d_ws;
    unsigned short* gT = (unsigned short*)ws;                          // 4 MB
    float* ssT = (float*)(ws + ((size_t)NB * NH * ND * NN * 2));
    float* sdT = ssT + (size_t)NB * NH * NN;

    gat_gemm_kernel<<<dim3(NH, 128), 256, 0, stream>>>(vertex, w_vert, attn_w,
                                                       gT, ssT, sdT);
    gat_attn_kernel<<<1024, 256, 0, stream>>>(gT, ssT, sdT, out);
}